// Round 1
// baseline (1725.927 us; speedup 1.0000x reference)
//
#include <hip/hip_runtime.h>

#define T_DIM 1024
#define B_DIM 512
#define OBS_DIM 64
#define H_DIM 128
#define G3 384
#define A_DIM 16
#define CT 128
#define NCHUNK 8

typedef __bf16 bf16;
typedef __attribute__((ext_vector_type(8))) __bf16 bf16x8;
typedef __attribute__((ext_vector_type(4))) float f32x4;

#define MFMA(a, b, c) __builtin_amdgcn_mfma_f32_16x16x32_bf16((a), (b), (c), 0, 0, 0)

__device__ __forceinline__ float sigm(float x) { return 1.0f / (1.0f + __expf(-x)); }
__device__ __forceinline__ float tanh_f(float x) { return 1.0f - 2.0f / (__expf(2.0f * x) + 1.0f); }

// ---------------- prep: bf16 transposed weights + h_state init ----------------
__global__ __launch_bounds__(256) void prep_k(
    const float* __restrict__ hidden, const int* __restrict__ dones,
    const float* __restrict__ W_emb, const float* __restrict__ Wi,
    const float* __restrict__ Wh, const float* __restrict__ Wa1,
    const float* __restrict__ Wa2, const float* __restrict__ Wc1,
    const float* __restrict__ Wc2,
    bf16* __restrict__ wembT, bf16* __restrict__ wiT, bf16* __restrict__ whT,
    bf16* __restrict__ wa1T, bf16* __restrict__ wa2T, bf16* __restrict__ wc1T,
    bf16* __restrict__ wc2T, float* __restrict__ h_state) {
  int i = blockIdx.x * 256 + threadIdx.x;
  if (i < 8192) { int n = i / OBS_DIM, k = i % OBS_DIM; wembT[i] = (bf16)W_emb[k * H_DIM + n]; return; }
  i -= 8192;
  if (i < 49152) { int g = i / H_DIM, k = i % H_DIM; wiT[i] = (bf16)Wi[k * G3 + g]; return; }
  i -= 49152;
  if (i < 49152) { int g = i / H_DIM, k = i % H_DIM; whT[i] = (bf16)Wh[k * G3 + g]; return; }
  i -= 49152;
  if (i < 16384) { int n = i / H_DIM, k = i % H_DIM; wa1T[i] = (bf16)Wa1[k * H_DIM + n]; return; }
  i -= 16384;
  if (i < 2048) { int a = i / H_DIM, k = i % H_DIM; wa2T[i] = (bf16)Wa2[k * A_DIM + a]; return; }
  i -= 2048;
  if (i < 16384) { int n = i / H_DIM, k = i % H_DIM; wc1T[i] = (bf16)Wc1[k * H_DIM + n]; return; }
  i -= 16384;
  if (i < 2048) { int r = i / H_DIM, k = i % H_DIM; wc2T[i] = (r == 0) ? (bf16)Wc2[k] : (bf16)0.0f; return; }
  i -= 2048;
  if (i < 65536) { int b = i / H_DIM; h_state[i] = dones[b] ? 0.0f : hidden[i]; return; }
}

// ---------------- phase1: xi = relu(obs@W_emb+b_emb)@Wi + bi  (bf16 out) ------
__global__ __launch_bounds__(256) void phase1_k(
    const float* __restrict__ obs, const float* __restrict__ b_emb,
    const float* __restrict__ bi, const bf16* __restrict__ wembT,
    const bf16* __restrict__ wiT, bf16* __restrict__ xi, int row_base) {
  __shared__ __align__(16) bf16 lds[4][16][392];  // per-wave strip, padded stride
  int tid = threadIdx.x;
  int wave = tid >> 6, lane = tid & 63;
  int nl = lane & 15, q = lane >> 4;
  int r0 = blockIdx.x * 64 + wave * 16;          // chunk-local row
  long grow = (long)row_base + r0 + nl;          // global row for A loads

  // A fragments from obs (f32 -> bf16)
  bf16x8 ao[2];
  const float* op = obs + grow * OBS_DIM;
#pragma unroll
  for (int kb = 0; kb < 2; ++kb) {
    float4 v0 = *(const float4*)(op + kb * 32 + q * 8);
    float4 v1 = *(const float4*)(op + kb * 32 + q * 8 + 4);
    bf16x8 f;
    f[0] = (bf16)v0.x; f[1] = (bf16)v0.y; f[2] = (bf16)v0.z; f[3] = (bf16)v0.w;
    f[4] = (bf16)v1.x; f[5] = (bf16)v1.y; f[6] = (bf16)v1.z; f[7] = (bf16)v1.w;
    ao[kb] = f;
  }
  // emb = relu(obs@W_emb + b_emb) -> LDS strip [16][128]
#pragma unroll
  for (int nt = 0; nt < 8; ++nt) {
    f32x4 c = {0.f, 0.f, 0.f, 0.f};
#pragma unroll
    for (int kb = 0; kb < 2; ++kb) {
      bf16x8 bfr = *(const bf16x8*)(wembT + (nt * 16 + nl) * OBS_DIM + kb * 32 + q * 8);
      c = MFMA(ao[kb], bfr, c);
    }
    float be = b_emb[nt * 16 + nl];
#pragma unroll
    for (int r = 0; r < 4; ++r) {
      float v = c[r] + be;
      lds[wave][q * 4 + r][nt * 16 + nl] = (bf16)(v > 0.f ? v : 0.f);
    }
  }
  // reload emb as A fragments (same wave; compiler inserts lgkm waits)
  bf16x8 ae[4];
#pragma unroll
  for (int kb = 0; kb < 4; ++kb) ae[kb] = *(const bf16x8*)&lds[wave][nl][kb * 32 + q * 8];

  // xi = emb@Wi + bi -> LDS strip [16][384]
#pragma unroll
  for (int nt = 0; nt < 24; ++nt) {
    f32x4 c = {0.f, 0.f, 0.f, 0.f};
#pragma unroll
    for (int kb = 0; kb < 4; ++kb) {
      bf16x8 bfr = *(const bf16x8*)(wiT + (nt * 16 + nl) * H_DIM + kb * 32 + q * 8);
      c = MFMA(ae[kb], bfr, c);
    }
    float bv = bi[nt * 16 + nl];
#pragma unroll
    for (int r = 0; r < 4; ++r) lds[wave][q * 4 + r][nt * 16 + nl] = (bf16)(c[r] + bv);
  }
  // coalesced strip copy to global (16 rows x 384 bf16 contiguous = 12 KiB)
  bf16* dst = xi + (long)r0 * G3;
#pragma unroll
  for (int it = 0; it < 12; ++it) {
    int e0 = (it * 64 + lane) * 8;
    int row = e0 / G3, col = e0 % G3;
    *(int4*)(dst + e0) = *(const int4*)&lds[wave][row][col];
  }
}

// ---------------- scan: GRU over CT steps, 2 chains per block ----------------
__global__ __launch_bounds__(256) void scan_k(
    const bf16* __restrict__ xi, const int* __restrict__ dones,
    const float* __restrict__ bh_n, const bf16* __restrict__ whT,
    float* __restrict__ h_state, bf16* __restrict__ y,
    float* __restrict__ hidden_out, int chunk) {
  __shared__ __align__(16) float h_f32[2][H_DIM];
  __shared__ __align__(16) bf16 h_bf[16][136];          // padded for bank spread
  __shared__ __align__(16) float hh[2][G3];
  __shared__ __align__(16) bf16 xibuf[2][8][2][G3];     // double-buffered 8-step xi
  __shared__ int dn[CT + 1][2];
  int tid = threadIdx.x;
  int wave = tid >> 6, lane = tid & 63;
  int nl = lane & 15, q = lane >> 4;
  int b0 = blockIdx.x * 2;

  for (int i = tid; i < 16 * 136; i += 256) h_bf[i / 136][i % 136] = (bf16)0.0f;
  float hv0 = h_state[b0 * H_DIM + tid];
  h_f32[tid >> 7][tid & 127] = hv0;
  for (int i = tid; i <= CT; i += 256) {
    int t = chunk * CT + i;
    dn[i][0] = (t < T_DIM) ? dones[t * B_DIM + b0] : 0;
    dn[i][1] = (t < T_DIM) ? dones[t * B_DIM + b0 + 1] : 0;
  }
  __syncthreads();
  h_bf[tid >> 7][tid & 127] = (bf16)hv0;   // rows 0,1 valid; rest stay zero

  // Wh B-fragments: register-stationary for the whole chunk (6 n-tiles/wave)
  bf16x8 wf[6][4];
#pragma unroll
  for (int j = 0; j < 6; ++j)
#pragma unroll
    for (int kb = 0; kb < 4; ++kb)
      wf[j][kb] = *(const bf16x8*)(whT + ((wave * 6 + j) * 16 + nl) * H_DIM + kb * 32 + q * 8);
  float bhn = bh_n[tid & 127];

  // first 8-step xi block
#pragma unroll
  for (int j = 0; j < 3; ++j) {
    int c16 = j * 256 + tid;
    int tt = c16 / 96, pos = c16 % 96;
    *(int4*)((bf16*)xibuf + tt * 2 * G3 + pos * 8) =
        *(const int4*)(xi + ((long)tt * B_DIM + b0) * G3 + pos * 8);
  }
  __syncthreads();

  int cur = 0;
  int b_el = tid >> 7, jj = tid & 127;
  for (int tb = 0; tb < CT; tb += 8) {
    int4 pf[3];
    bool hv_pf = (tb + 8 < CT);
    if (hv_pf) {
#pragma unroll
      for (int j = 0; j < 3; ++j) {
        int c16 = j * 256 + tid;
        int tt = c16 / 96, pos = c16 % 96;
        pf[j] = *(const int4*)(xi + ((long)(tb + 8 + tt) * B_DIM + b0) * G3 + pos * 8);
      }
    }
#pragma unroll
    for (int ts = 0; ts < 8; ++ts) {
      int t = tb + ts;
      bf16x8 ha[4];
#pragma unroll
      for (int kb = 0; kb < 4; ++kb) ha[kb] = *(const bf16x8*)&h_bf[nl][kb * 32 + q * 8];
      f32x4 c[6];
#pragma unroll
      for (int j = 0; j < 6; ++j) c[j] = (f32x4){0.f, 0.f, 0.f, 0.f};
#pragma unroll
      for (int kb = 0; kb < 4; ++kb)
#pragma unroll
        for (int j = 0; j < 6; ++j) c[j] = MFMA(ha[kb], wf[j][kb], c[j]);
      if (q == 0) {
#pragma unroll
        for (int j = 0; j < 6; ++j) {
          int n = (wave * 6 + j) * 16 + nl;
          hh[0][n] = c[j][0];   // D row0 = chain0
          hh[1][n] = c[j][1];   // D row1 = chain1
        }
      }
      __syncthreads();
      // elementwise GRU gates: 1 (b, jj) pair per thread
      float xr = (float)xibuf[cur][ts][b_el][jj];
      float xz = (float)xibuf[cur][ts][b_el][jj + 128];
      float xn = (float)xibuf[cur][ts][b_el][jj + 256];
      float hr = hh[b_el][jj], hz = hh[b_el][jj + 128], hn = hh[b_el][jj + 256];
      float hprev = h_f32[b_el][jj];
      float r = sigm(xr + hr);
      float z = sigm(xz + hz);
      float n = tanh_f(xn + r * (hn + bhn));
      float hnew = (1.f - z) * n + z * hprev;
      y[((long)t * B_DIM + b0 + b_el) * H_DIM + jj] = (bf16)hnew;
      if (chunk == NCHUNK - 1 && t == CT - 1)
        hidden_out[(b0 + b_el) * H_DIM + jj] = hnew;
      float heff = dn[t + 1][b_el] ? 0.f : hnew;  // reset applied for NEXT step
      h_f32[b_el][jj] = heff;
      h_bf[b_el][jj] = (bf16)heff;
      __syncthreads();
    }
    if (hv_pf) {
      int nb = cur ^ 1;
#pragma unroll
      for (int j = 0; j < 3; ++j) {
        int c16 = j * 256 + tid;
        int tt = c16 / 96, pos = c16 % 96;
        *(int4*)((bf16*)xibuf + nb * (8 * 2 * G3) + tt * 2 * G3 + pos * 8) = pf[j];
      }
      __syncthreads();
      cur = nb;
    }
  }
  h_state[b0 * H_DIM + tid] = h_f32[tid >> 7][tid & 127];
}

// ---------------- heads: actor + critic from y (bf16 MFMA) -------------------
__global__ __launch_bounds__(256) void heads_k(
    const bf16* __restrict__ y, const float* __restrict__ ba1,
    const float* __restrict__ ba2, const float* __restrict__ bc1,
    const float* __restrict__ bc2, const bf16* __restrict__ wa1T,
    const bf16* __restrict__ wa2T, const bf16* __restrict__ wc1T,
    const bf16* __restrict__ wc2T, float* __restrict__ logits,
    float* __restrict__ v, int t_base) {
  __shared__ __align__(16) bf16 s_a1[4][16][136];
  __shared__ __align__(16) float s_o[4][16][16];
  __shared__ __align__(16) float s_v[4][16];
  int tid = threadIdx.x, wave = tid >> 6, lane = tid & 63;
  int nl = lane & 15, q = lane >> 4;
  int r0 = blockIdx.x * 64 + wave * 16;          // chunk-local row
  long gr0 = (long)t_base * B_DIM + r0;          // global row

  bf16x8 ya[4];
#pragma unroll
  for (int kb = 0; kb < 4; ++kb)
    ya[kb] = *(const bf16x8*)(y + (long)(r0 + nl) * H_DIM + kb * 32 + q * 8);

  // actor layer 1
#pragma unroll
  for (int nt = 0; nt < 8; ++nt) {
    f32x4 c = {0.f, 0.f, 0.f, 0.f};
#pragma unroll
    for (int kb = 0; kb < 4; ++kb) {
      bf16x8 bfr = *(const bf16x8*)(wa1T + (nt * 16 + nl) * H_DIM + kb * 32 + q * 8);
      c = MFMA(ya[kb], bfr, c);
    }
    float bv = ba1[nt * 16 + nl];
#pragma unroll
    for (int r = 0; r < 4; ++r) {
      float val = c[r] + bv;
      s_a1[wave][q * 4 + r][nt * 16 + nl] = (bf16)(val > 0.f ? val : 0.f);
    }
  }
  bf16x8 a1f[4];
#pragma unroll
  for (int kb = 0; kb < 4; ++kb) a1f[kb] = *(const bf16x8*)&s_a1[wave][nl][kb * 32 + q * 8];
  // logits
  {
    f32x4 c = {0.f, 0.f, 0.f, 0.f};
#pragma unroll
    for (int kb = 0; kb < 4; ++kb) {
      bf16x8 bfr = *(const bf16x8*)(wa2T + nl * H_DIM + kb * 32 + q * 8);
      c = MFMA(a1f[kb], bfr, c);
    }
    float bv = ba2[nl];
#pragma unroll
    for (int r = 0; r < 4; ++r) s_o[wave][q * 4 + r][nl] = c[r] + bv;
  }
  // critic layer 1 (reuse strip; a1f already in regs)
#pragma unroll
  for (int nt = 0; nt < 8; ++nt) {
    f32x4 c = {0.f, 0.f, 0.f, 0.f};
#pragma unroll
    for (int kb = 0; kb < 4; ++kb) {
      bf16x8 bfr = *(const bf16x8*)(wc1T + (nt * 16 + nl) * H_DIM + kb * 32 + q * 8);
      c = MFMA(ya[kb], bfr, c);
    }
    float bv = bc1[nt * 16 + nl];
#pragma unroll
    for (int r = 0; r < 4; ++r) {
      float val = c[r] + bv;
      s_a1[wave][q * 4 + r][nt * 16 + nl] = (bf16)(val > 0.f ? val : 0.f);
    }
  }
  bf16x8 c1f[4];
#pragma unroll
  for (int kb = 0; kb < 4; ++kb) c1f[kb] = *(const bf16x8*)&s_a1[wave][nl][kb * 32 + q * 8];
  // v (Wc2 padded to 16 cols, col 0 real)
  {
    f32x4 c = {0.f, 0.f, 0.f, 0.f};
#pragma unroll
    for (int kb = 0; kb < 4; ++kb) {
      bf16x8 bfr = *(const bf16x8*)(wc2T + nl * H_DIM + kb * 32 + q * 8);
      c = MFMA(c1f[kb], bfr, c);
    }
    if (nl == 0) {
      float bv = bc2[0];
#pragma unroll
      for (int r = 0; r < 4; ++r) s_v[wave][q * 4 + r] = c[r] + bv;
    }
  }
  // coalesced writes
  *(int4*)(logits + gr0 * A_DIM + lane * 4) = *(const int4*)&s_o[wave][lane >> 2][(lane & 3) * 4];
  if (lane < 16) v[gr0 + lane] = s_v[wave][lane];
}

// ---------------- launch ------------------------------------------------------
extern "C" void kernel_launch(void* const* d_in, const int* in_sizes, int n_in,
                              void* d_out, int out_size, void* d_ws, size_t ws_size,
                              hipStream_t stream) {
  const float* hidden = (const float*)d_in[0];
  const float* obs    = (const float*)d_in[1];
  const int*   dones  = (const int*)d_in[2];
  const float* W_emb  = (const float*)d_in[3];
  const float* b_emb  = (const float*)d_in[4];
  const float* Wi     = (const float*)d_in[5];
  const float* bi     = (const float*)d_in[6];
  const float* Wh     = (const float*)d_in[7];
  const float* bh_n   = (const float*)d_in[8];
  const float* Wa1    = (const float*)d_in[9];
  const float* ba1    = (const float*)d_in[10];
  const float* Wa2    = (const float*)d_in[11];
  const float* ba2    = (const float*)d_in[12];
  const float* Wc1    = (const float*)d_in[13];
  const float* bc1    = (const float*)d_in[14];
  const float* Wc2    = (const float*)d_in[15];
  const float* bc2    = (const float*)d_in[16];

  float* out_hidden = (float*)d_out;
  float* out_logits = out_hidden + B_DIM * H_DIM;
  float* out_v      = out_logits + (long)T_DIM * B_DIM * A_DIM;

  char* ws = (char*)d_ws;
  bf16*  wembT   = (bf16*)(ws + 0);
  bf16*  wiT     = (bf16*)(ws + 16384);
  bf16*  whT     = (bf16*)(ws + 114688);
  bf16*  wa1T    = (bf16*)(ws + 212992);
  bf16*  wa2T    = (bf16*)(ws + 245760);
  bf16*  wc1T    = (bf16*)(ws + 249856);
  bf16*  wc2T    = (bf16*)(ws + 282624);
  float* h_state = (float*)(ws + 286720);
  bf16*  xi      = (bf16*)(ws + 548864);     // CT*B*384 bf16 = 50.3 MB
  bf16*  yb      = (bf16*)(ws + 50880512);   // CT*B*128 bf16 = 16.8 MB; total 67.7 MB

  prep_k<<<816, 256, 0, stream>>>(hidden, dones, W_emb, Wi, Wh, Wa1, Wa2, Wc1, Wc2,
                                  wembT, wiT, whT, wa1T, wa2T, wc1T, wc2T, h_state);
  for (int c = 0; c < NCHUNK; ++c) {
    phase1_k<<<(CT * B_DIM) / 64, 256, 0, stream>>>(obs, b_emb, bi, wembT, wiT, xi,
                                                    c * CT * B_DIM);
    scan_k<<<B_DIM / 2, 256, 0, stream>>>(xi, dones, bh_n, whT, h_state, yb,
                                          out_hidden, c);
    heads_k<<<(CT * B_DIM) / 64, 256, 0, stream>>>(yb, ba1, ba2, bc1, bc2, wa1T, wa2T,
                                                   wc1T, wc2T, out_logits, out_v, c * CT);
  }
  (void)in_sizes; (void)n_in; (void)out_size; (void)ws_size;
}